// Round 9
// baseline (315.594 us; speedup 1.0000x reference)
//
#include <hip/hip_runtime.h>
#include <math.h>

#define NB    4
#define CDIM  256
#define NSEQ  2304          // 48*48
#define NHEAD 8
#define HD    32
// SCALE * LOG2E folded into WqT at prep time
#define QSCALE (0.17677669529663687f * 1.4426950408889634f)
#define INV2048 4.8828125e-4f

typedef _Float16 f16;
typedef _Float16 f16x8 __attribute__((ext_vector_type(8)));
typedef _Float16 f16x4 __attribute__((ext_vector_type(4)));
typedef float    f32x4 __attribute__((ext_vector_type(4)));

// ---------------------------------------------------------------------------
// Kernel 0: prep — transpose + hi/lo f16 split of X and all weights.
//   X (B,256,N) f32  ->  X16h/X16l [mod][b][n][256]
//   Wq/Wkv/Wp (256 x J) -> WTh/WTl [mod][1024][256]:
//     rows 0..255 = WqT (QSCALE folded), 256..767 = WkvT, 768..1023 = WpT
// ---------------------------------------------------------------------------
__global__ __launch_bounds__(256) void prep_split(
    const float* __restrict__ X0, const float* __restrict__ X1,
    const float* __restrict__ Wq0, const float* __restrict__ Wkv0,
    const float* __restrict__ Wp0, const float* __restrict__ Wq1,
    const float* __restrict__ Wkv1, const float* __restrict__ Wp1,
    f16* __restrict__ X16h, f16* __restrict__ X16l,
    f16* __restrict__ WTh, f16* __restrict__ WTl)
{
  __shared__ float Ls[64][65];
  const int t = threadIdx.x;
  const int id = blockIdx.x;

  const float* in; int incols, c0, col0; size_t obase; f16 *oh, *ol;
  float scale = 1.f;
  if (id < 1152) {
    int mb = id / 144, rem = id % 144;
    int ct = rem / 36, nt = rem % 36;
    int mod = mb >> 2, b = mb & 3;
    in = (mod ? X1 : X0) + (size_t)b * 256 * NSEQ;
    incols = NSEQ; c0 = ct * 64; col0 = nt * 64;
    obase = (size_t)mb * NSEQ + col0;
    oh = X16h; ol = X16l;
  } else {
    int wid = id - 1152;
    int mod = wid >> 6, r = wid & 63;
    int jt, ct2, rowoff;
    if (r < 16) {
      in = mod ? Wq1 : Wq0; incols = 256; jt = r >> 2; ct2 = r & 3;
      rowoff = 0; scale = QSCALE;
    } else if (r < 48) {
      int rr = r - 16;
      in = mod ? Wkv1 : Wkv0; incols = 512; jt = rr >> 2; ct2 = rr & 3;
      rowoff = 256;
    } else {
      int rr = r - 48;
      in = mod ? Wp1 : Wp0; incols = 256; jt = rr >> 2; ct2 = rr & 3;
      rowoff = 768;
    }
    c0 = ct2 * 64; col0 = jt * 64;
    obase = (size_t)mod * 1024 + rowoff + col0;
    oh = WTh; ol = WTl;
  }

#pragma unroll
  for (int i = 0; i < 4; ++i) {
    int cl = (t >> 4) + i * 16;
    int n4 = (t & 15) * 4;
    *(float4*)&Ls[cl][n4] =
        *(const float4*)(in + (size_t)(c0 + cl) * incols + col0 + n4);
  }
  __syncthreads();
#pragma unroll
  for (int i = 0; i < 4; ++i) {
    int ll = (t >> 4) + i * 16;       // local out row (input col)
    int c4 = (t & 15) * 4;            // out col chunk (input row)
    f16x4 hv, lv;
#pragma unroll
    for (int j = 0; j < 4; ++j) {
      float v = Ls[c4 + j][ll] * scale;
      f16 hh = (f16)v;
      hv[j] = hh;
      lv[j] = (f16)((v - (float)hh) * 2048.0f);
    }
    size_t o = (obase + ll) * 256 + c0 + c4;
    *(f16x4*)(oh + o) = hv;
    *(f16x4*)(ol + o) = lv;
  }
}

// ---------------------------------------------------------------------------
// Kernel 1: QKV projection, LDS-tiled MFMA GEMM, 128j x 64n tile, with
// register prefetch of the next k-chunk (pattern proven in attn @ R8).
// hi/lo 3-MFMA split only where branch-0 logit precision needs it
// (Q mod0, K mod1); everything else single f16 MFMA.
// ---------------------------------------------------------------------------
__global__ __launch_bounds__(256) void proj_qkv_mfma(
    const f16* __restrict__ X16h, const f16* __restrict__ X16l,
    const f16* __restrict__ WTh, const f16* __restrict__ WTl,
    f16* __restrict__ Qh, f16* __restrict__ Ql,
    f16* __restrict__ Kh, f16* __restrict__ Kl, f16* __restrict__ Vt)
{
  __shared__ f16 WhS[128][32];
  __shared__ f16 WlS[128][32];
  __shared__ f16 XhS[64][32];
  __shared__ f16 XlS[64][32];

  const int zz = blockIdx.z, mod = zz >> 2, b = zz & 3;
  const int n0 = blockIdx.y * 64, j0 = blockIdx.x * 128;
  const int t = threadIdx.x;
  const int wave = t >> 6, lane = t & 63;
  const int col = lane & 15, quad = lane >> 4;

  const bool need_lo = (j0 < 256) ? (mod == 0)
                     : (j0 < 512) ? (mod == 1) : false;

  const size_t wbase = (size_t)mod * 1024 + j0;
  const size_t xbase = ((size_t)(mod * NB + b) * NSEQ + n0) * 256;

  f32x4 am[2][4], ac[2][4];
#pragma unroll
  for (int s = 0; s < 2; ++s)
#pragma unroll
    for (int tt = 0; tt < 4; ++tt) {
      am[s][tt] = (f32x4){0.f, 0.f, 0.f, 0.f};
      ac[s][tt] = (f32x4){0.f, 0.f, 0.f, 0.f};
    }

  const int wrow = t >> 1, wseg = (t & 1) * 16;   // W stage: 128 rows x 2 halves
  const int xrow = t >> 2, xseg = (t & 3) * 8;    // X stage: 64 rows x 4 segs

  const f16* wph = WTh + (wbase + wrow) * 256 + wseg;
  const f16* wpl = WTl + (wbase + wrow) * 256 + wseg;
  const f16* xph = X16h + xbase + (size_t)xrow * 256 + xseg;
  const f16* xpl = X16l + xbase + (size_t)xrow * 256 + xseg;

  // prefetch k-chunk 0
  f16x8 rwh0 = *(const f16x8*)(wph);
  f16x8 rwh1 = *(const f16x8*)(wph + 8);
  f16x8 rxh  = *(const f16x8*)(xph);
  f16x8 rwl0 = {}, rwl1 = {}, rxl = {};
  if (need_lo) {
    rwl0 = *(const f16x8*)(wpl);
    rwl1 = *(const f16x8*)(wpl + 8);
    rxl  = *(const f16x8*)(xpl);
  }

  for (int c0 = 0; c0 < 256; c0 += 32) {
    __syncthreads();
    *(f16x8*)&WhS[wrow][wseg]     = rwh0;
    *(f16x8*)&WhS[wrow][wseg + 8] = rwh1;
    *(f16x8*)&XhS[xrow][xseg]     = rxh;
    if (need_lo) {
      *(f16x8*)&WlS[wrow][wseg]     = rwl0;
      *(f16x8*)&WlS[wrow][wseg + 8] = rwl1;
      *(f16x8*)&XlS[xrow][xseg]     = rxl;
    }
    __syncthreads();

    // issue next chunk's loads now; they drain during the MFMAs below
    const int cn = (c0 + 32 < 256) ? c0 + 32 : 0;
    rwh0 = *(const f16x8*)(wph + cn);
    rwh1 = *(const f16x8*)(wph + cn + 8);
    rxh  = *(const f16x8*)(xph + cn);
    if (need_lo) {
      rwl0 = *(const f16x8*)(wpl + cn);
      rwl1 = *(const f16x8*)(wpl + cn + 8);
      rxl  = *(const f16x8*)(xpl + cn);
    }

    f16x8 Ah0 = *(const f16x8*)&WhS[wave * 32 + col][quad * 8];
    f16x8 Ah1 = *(const f16x8*)&WhS[wave * 32 + 16 + col][quad * 8];
    if (need_lo) {
      f16x8 Al0 = *(const f16x8*)&WlS[wave * 32 + col][quad * 8];
      f16x8 Al1 = *(const f16x8*)&WlS[wave * 32 + 16 + col][quad * 8];
#pragma unroll
      for (int tt = 0; tt < 4; ++tt) {
        f16x8 Bh = *(const f16x8*)&XhS[tt * 16 + col][quad * 8];
        f16x8 Bl = *(const f16x8*)&XlS[tt * 16 + col][quad * 8];
        am[0][tt] = __builtin_amdgcn_mfma_f32_16x16x32_f16(Ah0, Bh, am[0][tt], 0, 0, 0);
        ac[0][tt] = __builtin_amdgcn_mfma_f32_16x16x32_f16(Ah0, Bl, ac[0][tt], 0, 0, 0);
        ac[0][tt] = __builtin_amdgcn_mfma_f32_16x16x32_f16(Al0, Bh, ac[0][tt], 0, 0, 0);
        am[1][tt] = __builtin_amdgcn_mfma_f32_16x16x32_f16(Ah1, Bh, am[1][tt], 0, 0, 0);
        ac[1][tt] = __builtin_amdgcn_mfma_f32_16x16x32_f16(Ah1, Bl, ac[1][tt], 0, 0, 0);
        ac[1][tt] = __builtin_amdgcn_mfma_f32_16x16x32_f16(Al1, Bh, ac[1][tt], 0, 0, 0);
      }
    } else {
#pragma unroll
      for (int tt = 0; tt < 4; ++tt) {
        f16x8 Bh = *(const f16x8*)&XhS[tt * 16 + col][quad * 8];
        am[0][tt] = __builtin_amdgcn_mfma_f32_16x16x32_f16(Ah0, Bh, am[0][tt], 0, 0, 0);
        am[1][tt] = __builtin_amdgcn_mfma_f32_16x16x32_f16(Ah1, Bh, am[1][tt], 0, 0, 0);
      }
    }
  }

#pragma unroll
  for (int s = 0; s < 2; ++s) {
    const int jq = j0 + wave * 32 + s * 16 + quad * 4;
#pragma unroll
    for (int tt = 0; tt < 4; ++tt) {
      const int n = n0 + tt * 16 + col;
      float v[4];
#pragma unroll
      for (int r = 0; r < 4; ++r)
        v[r] = need_lo ? fmaf(ac[s][tt][r], INV2048, am[s][tt][r])
                       : am[s][tt][r];
      if (jq < 256) {
        f16x4 hv, lv;
#pragma unroll
        for (int r = 0; r < 4; ++r) {
          f16 hh = (f16)v[r]; hv[r] = hh;
          lv[r] = (f16)((v[r] - (float)hh) * 2048.0f);
        }
        *(f16x4*)(Qh + ((size_t)(mod * NB + b) * NSEQ + n) * 256 + jq) = hv;
        if (mod == 0)
          *(f16x4*)(Ql + ((size_t)b * NSEQ + n) * 256 + jq) = lv;
      } else if (jq < 512) {
        f16x4 hv, lv;
#pragma unroll
        for (int r = 0; r < 4; ++r) {
          f16 hh = (f16)v[r]; hv[r] = hh;
          lv[r] = (f16)((v[r] - (float)hh) * 2048.0f);
        }
        *(f16x4*)(Kh + ((size_t)(mod * NB + b) * NSEQ + n) * 256 + (jq - 256)) = hv;
        if (mod == 1)
          *(f16x4*)(Kl + ((size_t)b * NSEQ + n) * 256 + (jq - 256)) = lv;
      } else {
#pragma unroll
        for (int r = 0; r < 4; ++r)
          Vt[((size_t)(mod * NB + b) * 256 + (jq - 512 + r)) * NSEQ + n] = (f16)v[r];
      }
    }
  }
}

// ---------------------------------------------------------------------------
// Kernel 2: MFMA flash attention — R8-proven (256 thr, 4 waves, 128 q/block,
// PS stride-72, register prefetch).  UNCHANGED from R8.
// ---------------------------------------------------------------------------
__global__ __launch_bounds__(256, 4) void attn_mfma(
    const f16* __restrict__ Qh, const f16* __restrict__ Ql,
    const f16* __restrict__ Kh, const f16* __restrict__ Kl,
    const f16* __restrict__ Vt, const float* __restrict__ U,
    f16* __restrict__ A16)
{
  __shared__ f16 KhS[64][32];      // unpadded: dense b128 banking
  __shared__ f16 KlS[64][32];
  __shared__ f16 VtS[32][72];      // 32 d x 64 keys, pad 64->72
  __shared__ f16 PS[4][32][72];    // per-wave P: 32 q x 64 keys, stride 72

  const int branch = blockIdx.z;
  const int bh = blockIdx.y, b = bh >> 3, h = bh & 7;
  const int tid = threadIdx.x;
  const int wave = tid >> 6, lane = tid & 63;
  const int col = lane & 15, quad = lane >> 4;
  const int q0  = blockIdx.x * 128 + wave * 32;
  const int qr0 = q0 + col;
  const int qr1 = q0 + 16 + col;

  const int qmod = branch, kmod = 1 - branch;
  const size_t qbase = (size_t)(qmod * NB + b) * NSEQ * 256;
  const size_t kbase = (size_t)(kmod * NB + b) * NSEQ;
  const size_t kbaseL = (size_t)b * NSEQ;          // Kl is mod1-only
  const size_t vbase = (size_t)(kmod * NB + b) * 256;

  const f16x8 bqh0 = *(const f16x8*)(Qh + qbase + (size_t)qr0 * 256 + h * HD + quad * 8);
  const f16x8 bqh1 = *(const f16x8*)(Qh + qbase + (size_t)qr1 * 256 + h * HD + quad * 8);
  f16x8 bql0 = {}, bql1 = {};
  float uw0 = 1.0f, uw1 = 1.0f;
  if (branch == 0) {
    const size_t qbaseL = (size_t)b * NSEQ * 256;  // Ql is mod0-only
    bql0 = *(const f16x8*)(Ql + qbaseL + (size_t)qr0 * 256 + h * HD + quad * 8);
    bql1 = *(const f16x8*)(Ql + qbaseL + (size_t)qr1 * 256 + h * HD + quad * 8);
    uw0 = 1.0f / (U[b * NSEQ + qr0] + 1e-6f);
    uw1 = 1.0f / (U[b * NSEQ + qr1] + 1e-6f);
  }

  float m0 = -1e30f, l0 = 0.f, m1 = -1e30f, l1 = 0.f;
  f32x4 oc00 = {0.f,0.f,0.f,0.f}, oc01 = {0.f,0.f,0.f,0.f};
  f32x4 oc10 = {0.f,0.f,0.f,0.f}, oc11 = {0.f,0.f,0.f,0.f};
  const f32x4 z4 = {0.f,0.f,0.f,0.f};

  // per-thread staging slots
  const int krow = tid >> 2, kseg = (tid & 3) * 8;
  const int vrow = tid >> 3, vseg = (tid & 7) * 8;

  // prefetch chunk 0 into registers
  f16x8 pkh = *(const f16x8*)(Kh + (kbase + krow) * 256 + h * HD + kseg);
  f16x8 pkl = {};
  if (branch == 0)
    pkl = *(const f16x8*)(Kl + (kbaseL + krow) * 256 + h * HD + kseg);
  f16x8 pv = *(const f16x8*)(Vt + (vbase + h * HD + vrow) * NSEQ + vseg);

  for (int k0 = 0; k0 < NSEQ; k0 += 64) {
    __syncthreads();
    *(f16x8*)&KhS[krow][kseg] = pkh;
    if (branch == 0) *(f16x8*)&KlS[krow][kseg] = pkl;
    *(f16x8*)&VtS[vrow][vseg] = pv;
    __syncthreads();

    // issue next chunk's loads NOW; they drain during the compute below
    const int kn = (k0 + 64 < NSEQ) ? k0 + 64 : 0;
    pkh = *(const f16x8*)(Kh + (kbase + kn + krow) * 256 + h * HD + kseg);
    if (branch == 0)
      pkl = *(const f16x8*)(Kl + (kbaseL + kn + krow) * 256 + h * HD + kseg);
    pv = *(const f16x8*)(Vt + (vbase + h * HD + vrow) * NSEQ + kn + vseg);

    float p0[16], p1[16];
#pragma unroll
    for (int t = 0; t < 4; ++t) {
      f16x8 ah = *(const f16x8*)&KhS[t * 16 + col][quad * 8];
      f32x4 s0 = __builtin_amdgcn_mfma_f32_16x16x32_f16(ah, bqh0, z4, 0, 0, 0);
      f32x4 s1 = __builtin_amdgcn_mfma_f32_16x16x32_f16(ah, bqh1, z4, 0, 0, 0);
      if (branch == 0) {
        f16x8 al = *(const f16x8*)&KlS[t * 16 + col][quad * 8];
        f32x4 c0 = __builtin_amdgcn_mfma_f32_16x16x32_f16(ah, bql0, z4, 0, 0, 0);
        c0 = __builtin_amdgcn_mfma_f32_16x16x32_f16(al, bqh0, c0, 0, 0, 0);
        f32x4 c1 = __builtin_amdgcn_mfma_f32_16x16x32_f16(ah, bql1, z4, 0, 0, 0);
        c1 = __builtin_amdgcn_mfma_f32_16x16x32_f16(al, bqh1, c1, 0, 0, 0);
#pragma unroll
        for (int r = 0; r < 4; ++r) {
          p0[t * 4 + r] = fmaf(c0[r], INV2048, s0[r]);
          p1[t * 4 + r] = fmaf(c1[r], INV2048, s1[r]);
        }
      } else {
#pragma unroll
        for (int r = 0; r < 4; ++r) { p0[t * 4 + r] = s0[r]; p1[t * 4 + r] = s1[r]; }
      }
    }

#pragma unroll
    for (int g = 0; g < 2; ++g) {
      float* p = g ? p1 : p0;
      const float uw = g ? uw1 : uw0;
      float& m = g ? m1 : m0;
      float& l = g ? l1 : l0;
      f32x4& oa = g ? oc10 : oc00;
      f32x4& ob = g ? oc11 : oc01;

      float r0 = fmaxf(fmaxf(p[0], p[1]),  fmaxf(p[2], p[3]));
      float r1 = fmaxf(fmaxf(p[4], p[5]),  fmaxf(p[6], p[7]));
      float r2 = fmaxf(fmaxf(p[8], p[9]),  fmaxf(p[10], p[11]));
      float r3 = fmaxf(fmaxf(p[12], p[13]), fmaxf(p[14], p[15]));
      float cmax = fmaxf(fmaxf(r0, r1), fmaxf(r2, r3)) * uw;
      cmax = fmaxf(cmax, __shfl_xor(cmax, 16, 64));
      cmax = fmaxf(cmax, __shfl_xor(cmax, 32, 64));
      const float mn = fmaxf(m, cmax);
      const float alpha = exp2f(m - mn);
      m = mn;
      float lsA = 0.f, lsB = 0.f;
#pragma unroll
      for (int i = 0; i < 16; i += 2) {
        float eA = exp2f(fmaf(p[i],     uw, -mn));
        float eB = exp2f(fmaf(p[i + 1], uw, -mn));
        p[i] = eA; p[i + 1] = eB;
        lsA += eA; lsB += eB;
      }
      float ls = lsA + lsB;
      ls += __shfl_xor(ls, 16, 64);
      ls += __shfl_xor(ls, 32, 64);
      l = fmaf(l, alpha, ls);
#pragma unroll
      for (int r = 0; r < 4; ++r) { oa[r] *= alpha; ob[r] *= alpha; }

#pragma unroll
      for (int t = 0; t < 4; ++t) {
        f16x4 pk;
#pragma unroll
        for (int r = 0; r < 4; ++r) pk[r] = (f16)p[t * 4 + r];
        *(f16x4*)&PS[wave][g * 16 + col][t * 16 + quad * 4] = pk;
      }
    }

#pragma unroll
    for (int s = 0; s < 2; ++s) {
      f16x8 av0 = *(const f16x8*)&VtS[col][s * 32 + quad * 8];
      f16x8 av1 = *(const f16x8*)&VtS[16 + col][s * 32 + quad * 8];
      f16x8 bp0 = *(const f16x8*)&PS[wave][col][s * 32 + quad * 8];
      f16x8 bp1 = *(const f16x8*)&PS[wave][16 + col][s * 32 + quad * 8];
      oc00 = __builtin_amdgcn_mfma_f32_16x16x32_f16(av0, bp0, oc00, 0, 0, 0);
      oc01 = __builtin_amdgcn_mfma_f32_16x16x32_f16(av1, bp0, oc01, 0, 0, 0);
      oc10 = __builtin_amdgcn_mfma_f32_16x16x32_f16(av0, bp1, oc10, 0, 0, 0);
      oc11 = __builtin_amdgcn_mfma_f32_16x16x32_f16(av1, bp1, oc11, 0, 0, 0);
    }
  }

  const float i0 = 1.0f / l0, i1 = 1.0f / l1;
  f16* d0 = A16 + (((size_t)(branch * NB + b) * NSEQ) + qr0) * 256 + h * HD;
  f16* d1 = A16 + (((size_t)(branch * NB + b) * NSEQ) + qr1) * 256 + h * HD;
  f16x4 o00, o01, o10, o11;
#pragma unroll
  for (int r = 0; r < 4; ++r) {
    o00[r] = (f16)(oc00[r] * i0);
    o01[r] = (f16)(oc01[r] * i0);
    o10[r] = (f16)(oc10[r] * i1);
    o11[r] = (f16)(oc11[r] * i1);
  }
  *(f16x4*)(d0 + quad * 4)      = o00;
  *(f16x4*)(d0 + 16 + quad * 4) = o01;
  *(f16x4*)(d1 + quad * 4)      = o10;
  *(f16x4*)(d1 + 16 + quad * 4) = o11;
}

// ---------------------------------------------------------------------------
// Kernel 3: output projection, LDS-tiled MFMA GEMM with register prefetch.
// A = WpT[j][c] hi/lo, B = A16[n][c] single f16.  128j x 64n tile; 2-MFMA
// split; writes (B,C,N) fp32 output + bias directly.
// ---------------------------------------------------------------------------
__global__ __launch_bounds__(256) void proj_out_mfma(
    const f16* __restrict__ A16, const f16* __restrict__ WTh,
    const f16* __restrict__ WTl, const float* __restrict__ bp0,
    const float* __restrict__ bp1, float* __restrict__ O)
{
  __shared__ f16 WhS[128][32];
  __shared__ f16 WlS[128][32];
  __shared__ f16 AS[64][32];

  const int zz = blockIdx.z, mod = zz >> 2, b = zz & 3;  // mod == branch
  const int n0 = blockIdx.y * 64, j0 = blockIdx.x * 128;
  const int t = threadIdx.x;
  const int wave = t >> 6, lane = t & 63;
  const int col = lane & 15, quad = lane >> 4;

  const size_t wbase = (size_t)mod * 1024 + 768 + j0;
  const size_t abase = ((size_t)(mod * NB + b) * NSEQ + n0) * 256;

  f32x4 am[2][4], ac[2][4];
#pragma unroll
  for (int s = 0; s < 2; ++s)
#pragma unroll
    for (int tt = 0; tt < 4; ++tt) {
      am[s][tt] = (f32x4){0.f, 0.f, 0.f, 0.f};
      ac[s][tt] = (f32x4){0.f, 0.f, 0.f, 0.f};
    }

  const int wrow = t >> 1, wseg = (t & 1) * 16;
  const int xrow = t >> 2, xseg = (t & 3) * 8;

  const f16* wph = WTh + (wbase + wrow) * 256 + wseg;
  const f16* wpl = WTl + (wbase + wrow) * 256 + wseg;
  const f16* aph = A16 + abase + (size_t)xrow * 256 + xseg;

  // prefetch k-chunk 0
  f16x8 rwh0 = *(const f16x8*)(wph);
  f16x8 rwh1 = *(const f16x8*)(wph + 8);
  f16x8 rwl0 = *(const f16x8*)(wpl);
  f16x8 rwl1 = *(const f16x8*)(wpl + 8);
  f16x8 ra   = *(const f16x8*)(aph);

  for (int c0 = 0; c0 < 256; c0 += 32) {
    __syncthreads();
    *(f16x8*)&WhS[wrow][wseg]     = rwh0;
    *(f16x8*)&WhS[wrow][wseg + 8] = rwh1;
    *(f16x8*)&WlS[wrow][wseg]     = rwl0;
    *(f16x8*)&WlS[wrow][wseg + 8] = rwl1;
    *(f16x8*)&AS[xrow][xseg]      = ra;
    __syncthreads();

    const int cn = (c0 + 32 < 256) ? c0 + 32 : 0;
    rwh0 = *(const f16x8*)(wph + cn);
    rwh1 = *(const f16x8*)(wph + cn + 8);
    rwl0 = *(const f16x8*)(wpl + cn);
    rwl1 = *(const f16x8*)(wpl + cn + 8);
    ra   = *(const f16x8*)(aph + cn);

    f16x8 Ah0 = *(const f16x8*)&WhS[wave * 32 + col][quad * 8];
    f16x8 Al0 = *(const f16x8*)&WlS[wave * 32 + col][quad * 8];
    f16x8 Ah1 = *(const f16x8*)&WhS[wave * 32 + 16 + col][quad * 8];
    f16x8 Al1 = *(const f16x8*)&WlS[wave * 32 + 16 + col][quad * 8];
#pragma unroll
    for (int tt = 0; tt < 4; ++tt) {
      f16x8 Bh = *(const f16x8*)&AS[tt * 16 + col][quad * 8];
      am[0][tt] = __builtin_amdgcn_mfma_f32_16x16x32_f16(Ah0, Bh, am[0][tt], 0, 0, 0);
      ac[0][tt] = __builtin_amdgcn_mfma_f32_16x16x32_f16(Al0, Bh, ac[0][tt], 0, 0, 0);
      am[1][tt] = __builtin_amdgcn_mfma_f32_16x16x32_f16(Ah1, Bh, am[1][tt], 0, 0, 0);
      ac[1][tt] = __builtin_amdgcn_mfma_f32_16x16x32_f16(Al1, Bh, ac[1][tt], 0, 0, 0);
    }
  }

  const float* bp = mod ? bp1 : bp0;
  float* Ob = O + (size_t)(mod * NB + b) * CDIM * NSEQ;
#pragma unroll
  for (int s = 0; s < 2; ++s) {
    const int jq = j0 + wave * 32 + s * 16 + quad * 4;
    const float4 bias = *(const float4*)(bp + jq);
    const float bias_r[4] = {bias.x, bias.y, bias.z, bias.w};
#pragma unroll
    for (int tt = 0; tt < 4; ++tt) {
      const int n = n0 + tt * 16 + col;
#pragma unroll
      for (int r = 0; r < 4; ++r) {
        float v = fmaf(ac[s][tt][r], INV2048, am[s][tt][r]) + bias_r[r];
        Ob[(size_t)(jq + r) * NSEQ + n] = v;
      }
    }
  }
}

// ---------------------------------------------------------------------------
extern "C" void kernel_launch(void* const* d_in, const int* in_sizes, int n_in,
                              void* d_out, int out_size, void* d_ws, size_t ws_size,
                              hipStream_t stream) {
  (void)in_sizes; (void)n_in; (void)out_size; (void)ws_size;
  const float* img     = (const float*)d_in[0];
  const float* rad     = (const float*)d_in[1];
  const float* U       = (const float*)d_in[2];
  const float* Wq_img  = (const float*)d_in[3];
  const float* Wkv_rad = (const float*)d_in[4];
  const float* Wq_rad  = (const float*)d_in[5];
  const float* Wkv_img = (const float*)d_in[6];
  const float* Wp_img  = (const float*)d_in[7];
  const float* bp_img  = (const float*)d_in[8];
  const float* Wp_rad  = (const float*)d_in[9];
  const float* bp_rad  = (const float*)d_in[10];
  float* out = (float*)d_out;

  // Workspace (68.2 MB < proven 75.5 MB), all f16 elements (layout = R5..R8):
  //   X16h|X16l: [2][B][N][256]; WTh|WTl: [2][1024][256]
  //   Qh: [2][B][N][256]; Ql: [B][N][256] (mod0 only)
  //   Kh: [2][B][N][256]; Kl: [B][N][256] (mod1 only)
  //   Vt: [2][B][256][N]; A16: [2][B][N][256]
  const size_t NE = (size_t)2 * NB * NSEQ * 256;   // 4,718,592
  const size_t WE = (size_t)2 * 1024 * 256;        // 524,288
  f16* X16h = (f16*)d_ws;
  f16* X16l = X16h + NE;
  f16* WTh  = X16l + NE;
  f16* WTl  = WTh + WE;
  f16* Qh   = WTl + WE;
  f16* Ql   = Qh + NE;
  f16* Kh   = Ql + NE / 2;
  f16* Kl   = Kh + NE;
  f16* Vt   = Kl + NE / 2;
  f16* A16  = Vt + NE;

  prep_split<<<dim3(1280), 256, 0, stream>>>(
      img, rad, Wq_img, Wkv_img, Wp_img, Wq_rad, Wkv_rad, Wp_rad,
      X16h, X16l, WTh, WTl);

  dim3 gp(6, 36, 2 * NB);
  proj_qkv_mfma<<<gp, 256, 0, stream>>>(X16h, X16l, WTh, WTl,
                                        Qh, Ql, Kh, Kl, Vt);

  dim3 ga(NSEQ / 128, NB * NHEAD, 2);
  attn_mfma<<<ga, 256, 0, stream>>>(Qh, Ql, Kh, Kl, Vt, U, A16);

  dim3 go(2, 36, 2 * NB);
  proj_out_mfma<<<go, 256, 0, stream>>>(A16, WTh, WTl, bp_img, bp_rad, out);
}

// Round 10
// 279.544 us; speedup vs baseline: 1.1290x; 1.1290x over previous
//
#include <hip/hip_runtime.h>
#include <math.h>

#define NB    4
#define CDIM  256
#define NSEQ  2304          // 48*48
#define NHEAD 8
#define HD    32
// SCALE * LOG2E folded into WqT at prep time
#define QSCALE (0.17677669529663687f * 1.4426950408889634f)
#define INV2048 4.8828125e-4f

typedef _Float16 f16;
typedef _Float16 f16x8 __attribute__((ext_vector_type(8)));
typedef _Float16 f16x4 __attribute__((ext_vector_type(4)));
typedef float    f32x4 __attribute__((ext_vector_type(4)));

// exp2 as a single v_exp_f32 (plain exp2f w/o -ffast-math lowers to the
// multi-instruction ocml library routine — ~20 insts; this was the dominant
// VALU cost in attn through R9).
__device__ __forceinline__ float fast_exp2(float x) {
#if __has_builtin(__builtin_amdgcn_exp2f)
  return __builtin_amdgcn_exp2f(x);
#else
  return exp2f(x);
#endif
}

// ---------------------------------------------------------------------------
// Kernel 0: prep — transpose + hi/lo f16 split of X and all weights.
//   X (B,256,N) f32  ->  X16h/X16l [mod][b][n][256]
//   Wq/Wkv/Wp (256 x J) -> WTh/WTl [mod][1024][256]:
//     rows 0..255 = WqT (QSCALE folded), 256..767 = WkvT, 768..1023 = WpT
// ---------------------------------------------------------------------------
__global__ __launch_bounds__(256) void prep_split(
    const float* __restrict__ X0, const float* __restrict__ X1,
    const float* __restrict__ Wq0, const float* __restrict__ Wkv0,
    const float* __restrict__ Wp0, const float* __restrict__ Wq1,
    const float* __restrict__ Wkv1, const float* __restrict__ Wp1,
    f16* __restrict__ X16h, f16* __restrict__ X16l,
    f16* __restrict__ WTh, f16* __restrict__ WTl)
{
  __shared__ float Ls[64][65];
  const int t = threadIdx.x;
  const int id = blockIdx.x;

  const float* in; int incols, c0, col0; size_t obase; f16 *oh, *ol;
  float scale = 1.f;
  if (id < 1152) {
    int mb = id / 144, rem = id % 144;
    int ct = rem / 36, nt = rem % 36;
    int mod = mb >> 2, b = mb & 3;
    in = (mod ? X1 : X0) + (size_t)b * 256 * NSEQ;
    incols = NSEQ; c0 = ct * 64; col0 = nt * 64;
    obase = (size_t)mb * NSEQ + col0;
    oh = X16h; ol = X16l;
  } else {
    int wid = id - 1152;
    int mod = wid >> 6, r = wid & 63;
    int jt, ct2, rowoff;
    if (r < 16) {
      in = mod ? Wq1 : Wq0; incols = 256; jt = r >> 2; ct2 = r & 3;
      rowoff = 0; scale = QSCALE;
    } else if (r < 48) {
      int rr = r - 16;
      in = mod ? Wkv1 : Wkv0; incols = 512; jt = rr >> 2; ct2 = rr & 3;
      rowoff = 256;
    } else {
      int rr = r - 48;
      in = mod ? Wp1 : Wp0; incols = 256; jt = rr >> 2; ct2 = rr & 3;
      rowoff = 768;
    }
    c0 = ct2 * 64; col0 = jt * 64;
    obase = (size_t)mod * 1024 + rowoff + col0;
    oh = WTh; ol = WTl;
  }

#pragma unroll
  for (int i = 0; i < 4; ++i) {
    int cl = (t >> 4) + i * 16;
    int n4 = (t & 15) * 4;
    *(float4*)&Ls[cl][n4] =
        *(const float4*)(in + (size_t)(c0 + cl) * incols + col0 + n4);
  }
  __syncthreads();
#pragma unroll
  for (int i = 0; i < 4; ++i) {
    int ll = (t >> 4) + i * 16;       // local out row (input col)
    int c4 = (t & 15) * 4;            // out col chunk (input row)
    f16x4 hv, lv;
#pragma unroll
    for (int j = 0; j < 4; ++j) {
      float v = Ls[c4 + j][ll] * scale;
      f16 hh = (f16)v;
      hv[j] = hh;
      lv[j] = (f16)((v - (float)hh) * 2048.0f);
    }
    size_t o = (obase + ll) * 256 + c0 + c4;
    *(f16x4*)(oh + o) = hv;
    *(f16x4*)(ol + o) = lv;
  }
}

// ---------------------------------------------------------------------------
// Kernel 1: QKV projection, LDS-tiled MFMA GEMM (R8-proven, no prefetch —
// R9 showed prefetch is neutral here).  128j x 64n tile.  hi/lo 3-MFMA split
// only where branch-0 logit precision needs it (Q mod0, K mod1).
// ---------------------------------------------------------------------------
__global__ __launch_bounds__(256) void proj_qkv_mfma(
    const f16* __restrict__ X16h, const f16* __restrict__ X16l,
    const f16* __restrict__ WTh, const f16* __restrict__ WTl,
    f16* __restrict__ Qh, f16* __restrict__ Ql,
    f16* __restrict__ Kh, f16* __restrict__ Kl, f16* __restrict__ Vt)
{
  __shared__ f16 WhS[128][32];
  __shared__ f16 WlS[128][32];
  __shared__ f16 XhS[64][32];
  __shared__ f16 XlS[64][32];

  const int zz = blockIdx.z, mod = zz >> 2, b = zz & 3;
  const int n0 = blockIdx.y * 64, j0 = blockIdx.x * 128;
  const int t = threadIdx.x;
  const int wave = t >> 6, lane = t & 63;
  const int col = lane & 15, quad = lane >> 4;

  const bool need_lo = (j0 < 256) ? (mod == 0)
                     : (j0 < 512) ? (mod == 1) : false;

  const size_t wbase = (size_t)mod * 1024 + j0;
  const size_t xbase = ((size_t)(mod * NB + b) * NSEQ + n0) * 256;

  f32x4 am[2][4], ac[2][4];
#pragma unroll
  for (int s = 0; s < 2; ++s)
#pragma unroll
    for (int tt = 0; tt < 4; ++tt) {
      am[s][tt] = (f32x4){0.f, 0.f, 0.f, 0.f};
      ac[s][tt] = (f32x4){0.f, 0.f, 0.f, 0.f};
    }

  const int wrow = t >> 1, wseg = (t & 1) * 16;   // W stage: 128 rows x 2 halves
  const int xrow = t >> 2, xseg = (t & 3) * 8;    // X stage: 64 rows x 4 segs

  for (int c0 = 0; c0 < 256; c0 += 32) {
    __syncthreads();
    *(f16x8*)&WhS[wrow][wseg] =
        *(const f16x8*)(WTh + (wbase + wrow) * 256 + c0 + wseg);
    *(f16x8*)&WhS[wrow][wseg + 8] =
        *(const f16x8*)(WTh + (wbase + wrow) * 256 + c0 + wseg + 8);
    *(f16x8*)&XhS[xrow][xseg] =
        *(const f16x8*)(X16h + xbase + (size_t)xrow * 256 + c0 + xseg);
    if (need_lo) {
      *(f16x8*)&WlS[wrow][wseg] =
          *(const f16x8*)(WTl + (wbase + wrow) * 256 + c0 + wseg);
      *(f16x8*)&WlS[wrow][wseg + 8] =
          *(const f16x8*)(WTl + (wbase + wrow) * 256 + c0 + wseg + 8);
      *(f16x8*)&XlS[xrow][xseg] =
          *(const f16x8*)(X16l + xbase + (size_t)xrow * 256 + c0 + xseg);
    }
    __syncthreads();

    f16x8 Ah0 = *(const f16x8*)&WhS[wave * 32 + col][quad * 8];
    f16x8 Ah1 = *(const f16x8*)&WhS[wave * 32 + 16 + col][quad * 8];
    if (need_lo) {
      f16x8 Al0 = *(const f16x8*)&WlS[wave * 32 + col][quad * 8];
      f16x8 Al1 = *(const f16x8*)&WlS[wave * 32 + 16 + col][quad * 8];
#pragma unroll
      for (int tt = 0; tt < 4; ++tt) {
        f16x8 Bh = *(const f16x8*)&XhS[tt * 16 + col][quad * 8];
        f16x8 Bl = *(const f16x8*)&XlS[tt * 16 + col][quad * 8];
        am[0][tt] = __builtin_amdgcn_mfma_f32_16x16x32_f16(Ah0, Bh, am[0][tt], 0, 0, 0);
        ac[0][tt] = __builtin_amdgcn_mfma_f32_16x16x32_f16(Ah0, Bl, ac[0][tt], 0, 0, 0);
        ac[0][tt] = __builtin_amdgcn_mfma_f32_16x16x32_f16(Al0, Bh, ac[0][tt], 0, 0, 0);
        am[1][tt] = __builtin_amdgcn_mfma_f32_16x16x32_f16(Ah1, Bh, am[1][tt], 0, 0, 0);
        ac[1][tt] = __builtin_amdgcn_mfma_f32_16x16x32_f16(Ah1, Bl, ac[1][tt], 0, 0, 0);
        ac[1][tt] = __builtin_amdgcn_mfma_f32_16x16x32_f16(Al1, Bh, ac[1][tt], 0, 0, 0);
      }
    } else {
#pragma unroll
      for (int tt = 0; tt < 4; ++tt) {
        f16x8 Bh = *(const f16x8*)&XhS[tt * 16 + col][quad * 8];
        am[0][tt] = __builtin_amdgcn_mfma_f32_16x16x32_f16(Ah0, Bh, am[0][tt], 0, 0, 0);
        am[1][tt] = __builtin_amdgcn_mfma_f32_16x16x32_f16(Ah1, Bh, am[1][tt], 0, 0, 0);
      }
    }
  }

#pragma unroll
  for (int s = 0; s < 2; ++s) {
    const int jq = j0 + wave * 32 + s * 16 + quad * 4;
#pragma unroll
    for (int tt = 0; tt < 4; ++tt) {
      const int n = n0 + tt * 16 + col;
      float v[4];
#pragma unroll
      for (int r = 0; r < 4; ++r)
        v[r] = need_lo ? fmaf(ac[s][tt][r], INV2048, am[s][tt][r])
                       : am[s][tt][r];
      if (jq < 256) {
        f16x4 hv, lv;
#pragma unroll
        for (int r = 0; r < 4; ++r) {
          f16 hh = (f16)v[r]; hv[r] = hh;
          lv[r] = (f16)((v[r] - (float)hh) * 2048.0f);
        }
        *(f16x4*)(Qh + ((size_t)(mod * NB + b) * NSEQ + n) * 256 + jq) = hv;
        if (mod == 0)
          *(f16x4*)(Ql + ((size_t)b * NSEQ + n) * 256 + jq) = lv;
      } else if (jq < 512) {
        f16x4 hv, lv;
#pragma unroll
        for (int r = 0; r < 4; ++r) {
          f16 hh = (f16)v[r]; hv[r] = hh;
          lv[r] = (f16)((v[r] - (float)hh) * 2048.0f);
        }
        *(f16x4*)(Kh + ((size_t)(mod * NB + b) * NSEQ + n) * 256 + (jq - 256)) = hv;
        if (mod == 1)
          *(f16x4*)(Kl + ((size_t)b * NSEQ + n) * 256 + (jq - 256)) = lv;
      } else {
#pragma unroll
        for (int r = 0; r < 4; ++r)
          Vt[((size_t)(mod * NB + b) * 256 + (jq - 512 + r)) * NSEQ + n] = (f16)v[r];
      }
    }
  }
}

// ---------------------------------------------------------------------------
// Kernel 2: MFMA flash attention — R8 structure (256 thr, 4 waves, 128 q/blk,
// PS stride-72, register prefetch), with exp2f -> v_exp_f32 (fast_exp2).
// ---------------------------------------------------------------------------
__global__ __launch_bounds__(256, 4) void attn_mfma(
    const f16* __restrict__ Qh, const f16* __restrict__ Ql,
    const f16* __restrict__ Kh, const f16* __restrict__ Kl,
    const f16* __restrict__ Vt, const float* __restrict__ U,
    f16* __restrict__ A16)
{
  __shared__ f16 KhS[64][32];      // unpadded: dense b128 banking
  __shared__ f16 KlS[64][32];
  __shared__ f16 VtS[32][72];      // 32 d x 64 keys, pad 64->72
  __shared__ f16 PS[4][32][72];    // per-wave P: 32 q x 64 keys, stride 72

  const int branch = blockIdx.z;
  const int bh = blockIdx.y, b = bh >> 3, h = bh & 7;
  const int tid = threadIdx.x;
  const int wave = tid >> 6, lane = tid & 63;
  const int col = lane & 15, quad = lane >> 4;
  const int q0  = blockIdx.x * 128 + wave * 32;
  const int qr0 = q0 + col;
  const int qr1 = q0 + 16 + col;

  const int qmod = branch, kmod = 1 - branch;
  const size_t qbase = (size_t)(qmod * NB + b) * NSEQ * 256;
  const size_t kbase = (size_t)(kmod * NB + b) * NSEQ;
  const size_t kbaseL = (size_t)b * NSEQ;          // Kl is mod1-only
  const size_t vbase = (size_t)(kmod * NB + b) * 256;

  const f16x8 bqh0 = *(const f16x8*)(Qh + qbase + (size_t)qr0 * 256 + h * HD + quad * 8);
  const f16x8 bqh1 = *(const f16x8*)(Qh + qbase + (size_t)qr1 * 256 + h * HD + quad * 8);
  f16x8 bql0 = {}, bql1 = {};
  float uw0 = 1.0f, uw1 = 1.0f;
  if (branch == 0) {
    const size_t qbaseL = (size_t)b * NSEQ * 256;  // Ql is mod0-only
    bql0 = *(const f16x8*)(Ql + qbaseL + (size_t)qr0 * 256 + h * HD + quad * 8);
    bql1 = *(const f16x8*)(Ql + qbaseL + (size_t)qr1 * 256 + h * HD + quad * 8);
    uw0 = 1.0f / (U[b * NSEQ + qr0] + 1e-6f);
    uw1 = 1.0f / (U[b * NSEQ + qr1] + 1e-6f);
  }

  float m0 = -1e30f, l0 = 0.f, m1 = -1e30f, l1 = 0.f;
  f32x4 oc00 = {0.f,0.f,0.f,0.f}, oc01 = {0.f,0.f,0.f,0.f};
  f32x4 oc10 = {0.f,0.f,0.f,0.f}, oc11 = {0.f,0.f,0.f,0.f};
  const f32x4 z4 = {0.f,0.f,0.f,0.f};

  // per-thread staging slots
  const int krow = tid >> 2, kseg = (tid & 3) * 8;
  const int vrow = tid >> 3, vseg = (tid & 7) * 8;

  // prefetch chunk 0 into registers
  f16x8 pkh = *(const f16x8*)(Kh + (kbase + krow) * 256 + h * HD + kseg);
  f16x8 pkl = {};
  if (branch == 0)
    pkl = *(const f16x8*)(Kl + (kbaseL + krow) * 256 + h * HD + kseg);
  f16x8 pv = *(const f16x8*)(Vt + (vbase + h * HD + vrow) * NSEQ + vseg);

  for (int k0 = 0; k0 < NSEQ; k0 += 64) {
    __syncthreads();
    *(f16x8*)&KhS[krow][kseg] = pkh;
    if (branch == 0) *(f16x8*)&KlS[krow][kseg] = pkl;
    *(f16x8*)&VtS[vrow][vseg] = pv;
    __syncthreads();

    // issue next chunk's loads NOW; they drain during the compute below
    const int kn = (k0 + 64 < NSEQ) ? k0 + 64 : 0;
    pkh = *(const f16x8*)(Kh + (kbase + kn + krow) * 256 + h * HD + kseg);
    if (branch == 0)
      pkl = *(const f16x8*)(Kl + (kbaseL + kn + krow) * 256 + h * HD + kseg);
    pv = *(const f16x8*)(Vt + (vbase + h * HD + vrow) * NSEQ + kn + vseg);

    float p0[16], p1[16];
#pragma unroll
    for (int t = 0; t < 4; ++t) {
      f16x8 ah = *(const f16x8*)&KhS[t * 16 + col][quad * 8];
      f32x4 s0 = __builtin_amdgcn_mfma_f32_16x16x32_f16(ah, bqh0, z4, 0, 0, 0);
      f32x4 s1 = __builtin_amdgcn_mfma_f32_16x16x32_f16(ah, bqh1, z4, 0, 0, 0);
      if (branch == 0) {
        f16x8 al = *(const f16x8*)&KlS[t * 16 + col][quad * 8];
        f32x4 c0 = __builtin_amdgcn_mfma_f32_16x16x32_f16(ah, bql0, z4, 0, 0, 0);
        c0 = __builtin_amdgcn_mfma_f32_16x16x32_f16(al, bqh0, c0, 0, 0, 0);
        f32x4 c1 = __builtin_amdgcn_mfma_f32_16x16x32_f16(ah, bql1, z4, 0, 0, 0);
        c1 = __builtin_amdgcn_mfma_f32_16x16x32_f16(al, bqh1, c1, 0, 0, 0);
#pragma unroll
        for (int r = 0; r < 4; ++r) {
          p0[t * 4 + r] = fmaf(c0[r], INV2048, s0[r]);
          p1[t * 4 + r] = fmaf(c1[r], INV2048, s1[r]);
        }
      } else {
#pragma unroll
        for (int r = 0; r < 4; ++r) { p0[t * 4 + r] = s0[r]; p1[t * 4 + r] = s1[r]; }
      }
    }

#pragma unroll
    for (int g = 0; g < 2; ++g) {
      float* p = g ? p1 : p0;
      const float uw = g ? uw1 : uw0;
      float& m = g ? m1 : m0;
      float& l = g ? l1 : l0;
      f32x4& oa = g ? oc10 : oc00;
      f32x4& ob = g ? oc11 : oc01;

      float r0 = fmaxf(fmaxf(p[0], p[1]),  fmaxf(p[2], p[3]));
      float r1 = fmaxf(fmaxf(p[4], p[5]),  fmaxf(p[6], p[7]));
      float r2 = fmaxf(fmaxf(p[8], p[9]),  fmaxf(p[10], p[11]));
      float r3 = fmaxf(fmaxf(p[12], p[13]), fmaxf(p[14], p[15]));
      float cmax = fmaxf(fmaxf(r0, r1), fmaxf(r2, r3)) * uw;
      cmax = fmaxf(cmax, __shfl_xor(cmax, 16, 64));
      cmax = fmaxf(cmax, __shfl_xor(cmax, 32, 64));
      const float mn = fmaxf(m, cmax);
      const float alpha = fast_exp2(m - mn);
      m = mn;
      float lsA = 0.f, lsB = 0.f;
#pragma unroll
      for (int i = 0; i < 16; i += 2) {
        float eA = fast_exp2(fmaf(p[i],     uw, -mn));
        float eB = fast_exp2(fmaf(p[i + 1], uw, -mn));
        p[i] = eA; p[i + 1] = eB;
        lsA += eA; lsB += eB;
      }
      float ls = lsA + lsB;
      ls += __shfl_xor(ls, 16, 64);
      ls += __shfl_xor(ls, 32, 64);
      l = fmaf(l, alpha, ls);
#pragma unroll
      for (int r = 0; r < 4; ++r) { oa[r] *= alpha; ob[r] *= alpha; }

#pragma unroll
      for (int t = 0; t < 4; ++t) {
        f16x4 pk;
#pragma unroll
        for (int r = 0; r < 4; ++r) pk[r] = (f16)p[t * 4 + r];
        *(f16x4*)&PS[wave][g * 16 + col][t * 16 + quad * 4] = pk;
      }
    }

#pragma unroll
    for (int s = 0; s < 2; ++s) {
      f16x8 av0 = *(const f16x8*)&VtS[col][s * 32 + quad * 8];
      f16x8 av1 = *(const f16x8*)&VtS[16 + col][s * 32 + quad * 8];
      f16x8 bp0 = *(const f16x8*)&PS[wave][col][s * 32 + quad * 8];
      f16x8 bp1 = *(const f16x8*)&PS[wave][16 + col][s * 32 + quad * 8];
      oc00 = __builtin_amdgcn_mfma_f32_16x16x32_f16(av0, bp0, oc00, 0, 0, 0);
      oc01 = __builtin_amdgcn_mfma_f32_16x16x32_f16(av1, bp0, oc01, 0, 0, 0);
      oc10 = __builtin_amdgcn_mfma_f32_16x16x32_f16(av0, bp1, oc10, 0, 0, 0);
      oc11 = __builtin_amdgcn_mfma_f32_16x16x32_f16(av1, bp1, oc11, 0, 0, 0);
    }
  }

  const float i0 = 1.0f / l0, i1 = 1.0f / l1;
  f16* d0 = A16 + (((size_t)(branch * NB + b) * NSEQ) + qr0) * 256 + h * HD;
  f16* d1 = A16 + (((size_t)(branch * NB + b) * NSEQ) + qr1) * 256 + h * HD;
  f16x4 o00, o01, o10, o11;
#pragma unroll
  for (int r = 0; r < 4; ++r) {
    o00[r] = (f16)(oc00[r] * i0);
    o01[r] = (f16)(oc01[r] * i0);
    o10[r] = (f16)(oc10[r] * i1);
    o11[r] = (f16)(oc11[r] * i1);
  }
  *(f16x4*)(d0 + quad * 4)      = o00;
  *(f16x4*)(d0 + 16 + quad * 4) = o01;
  *(f16x4*)(d1 + quad * 4)      = o10;
  *(f16x4*)(d1 + 16 + quad * 4) = o11;
}

// ---------------------------------------------------------------------------
// Kernel 3: output projection, LDS-tiled MFMA GEMM (R8-proven, no prefetch).
// A = WpT[j][c] hi/lo, B = A16[n][c] single f16.  128j x 64n tile; 2-MFMA
// split; writes (B,C,N) fp32 output + bias directly.
// ---------------------------------------------------------------------------
__global__ __launch_bounds__(256) void proj_out_mfma(
    const f16* __restrict__ A16, const f16* __restrict__ WTh,
    const f16* __restrict__ WTl, const float* __restrict__ bp0,
    const float* __restrict__ bp1, float* __restrict__ O)
{
  __shared__ f16 WhS[128][32];
  __shared__ f16 WlS[128][32];
  __shared__ f16 AS[64][32];

  const int zz = blockIdx.z, mod = zz >> 2, b = zz & 3;  // mod == branch
  const int n0 = blockIdx.y * 64, j0 = blockIdx.x * 128;
  const int t = threadIdx.x;
  const int wave = t >> 6, lane = t & 63;
  const int col = lane & 15, quad = lane >> 4;

  const size_t wbase = (size_t)mod * 1024 + 768 + j0;
  const size_t abase = ((size_t)(mod * NB + b) * NSEQ + n0) * 256;

  f32x4 am[2][4], ac[2][4];
#pragma unroll
  for (int s = 0; s < 2; ++s)
#pragma unroll
    for (int tt = 0; tt < 4; ++tt) {
      am[s][tt] = (f32x4){0.f, 0.f, 0.f, 0.f};
      ac[s][tt] = (f32x4){0.f, 0.f, 0.f, 0.f};
    }

  const int wrow = t >> 1, wseg = (t & 1) * 16;
  const int xrow = t >> 2, xseg = (t & 3) * 8;

  for (int c0 = 0; c0 < 256; c0 += 32) {
    __syncthreads();
    *(f16x8*)&WhS[wrow][wseg] =
        *(const f16x8*)(WTh + (wbase + wrow) * 256 + c0 + wseg);
    *(f16x8*)&WhS[wrow][wseg + 8] =
        *(const f16x8*)(WTh + (wbase + wrow) * 256 + c0 + wseg + 8);
    *(f16x8*)&WlS[wrow][wseg] =
        *(const f16x8*)(WTl + (wbase + wrow) * 256 + c0 + wseg);
    *(f16x8*)&WlS[wrow][wseg + 8] =
        *(const f16x8*)(WTl + (wbase + wrow) * 256 + c0 + wseg + 8);
    *(f16x8*)&AS[xrow][xseg] =
        *(const f16x8*)(A16 + abase + (size_t)xrow * 256 + c0 + xseg);
    __syncthreads();

    f16x8 Ah0 = *(const f16x8*)&WhS[wave * 32 + col][quad * 8];
    f16x8 Al0 = *(const f16x8*)&WlS[wave * 32 + col][quad * 8];
    f16x8 Ah1 = *(const f16x8*)&WhS[wave * 32 + 16 + col][quad * 8];
    f16x8 Al1 = *(const f16x8*)&WlS[wave * 32 + 16 + col][quad * 8];
#pragma unroll
    for (int tt = 0; tt < 4; ++tt) {
      f16x8 Bh = *(const f16x8*)&AS[tt * 16 + col][quad * 8];
      am[0][tt] = __builtin_amdgcn_mfma_f32_16x16x32_f16(Ah0, Bh, am[0][tt], 0, 0, 0);
      ac[0][tt] = __builtin_amdgcn_mfma_f32_16x16x32_f16(Al0, Bh, ac[0][tt], 0, 0, 0);
      am[1][tt] = __builtin_amdgcn_mfma_f32_16x16x32_f16(Ah1, Bh, am[1][tt], 0, 0, 0);
      ac[1][tt] = __builtin_amdgcn_mfma_f32_16x16x32_f16(Al1, Bh, ac[1][tt], 0, 0, 0);
    }
  }

  const float* bp = mod ? bp1 : bp0;
  float* Ob = O + (size_t)(mod * NB + b) * CDIM * NSEQ;
#pragma unroll
  for (int s = 0; s < 2; ++s) {
    const int jq = j0 + wave * 32 + s * 16 + quad * 4;
    const float4 bias = *(const float4*)(bp + jq);
    const float bias_r[4] = {bias.x, bias.y, bias.z, bias.w};
#pragma unroll
    for (int tt = 0; tt < 4; ++tt) {
      const int n = n0 + tt * 16 + col;
#pragma unroll
      for (int r = 0; r < 4; ++r) {
        float v = fmaf(ac[s][tt][r], INV2048, am[s][tt][r]) + bias_r[r];
        Ob[(size_t)(jq + r) * NSEQ + n] = v;
      }
    }
  }
}

// ---------------------------------------------------------------------------
extern "C" void kernel_launch(void* const* d_in, const int* in_sizes, int n_in,
                              void* d_out, int out_size, void* d_ws, size_t ws_size,
                              hipStream_t stream) {
  (void)in_sizes; (void)n_in; (void)out_size; (void)ws_size;
  const float* img     = (const float*)d_in[0];
  const float* rad     = (const float*)d_in[1];
  const float* U       = (const float*)d_in[2];
  const float* Wq_img  = (const float*)d_in[3];
  const float* Wkv_rad = (const float*)d_in[4];
  const float* Wq_rad  = (const float*)d_in[5];
  const float* Wkv_img = (const float*)d_in[6];
  const float* Wp_img  = (const float*)d_in[7];
  const float* bp_img  = (const float*)d_in[8];
  const float* Wp_rad  = (const float*)d_in[9];
  const float* bp_rad  = (const float*)d_in[10];
  float* out = (float*)d_out;

  // Workspace (68.2 MB < proven 75.5 MB), all f16 elements (layout = R5..R9):
  //   X16h|X16l: [2][B][N][256]; WTh|WTl: [2][1024][256]
  //   Qh: [2][B][N][256]; Ql: [B][N][256] (mod0 only)
  //   Kh: [2][B][N][256]; Kl: [B][N][256] (mod1 only)
  //   Vt: [2][B][256][N]; A16: [2][B][N][256]
  const size_t NE = (size_t)2 * NB * NSEQ * 256;   // 4,718,592
  const size_t WE = (size_t)2 * 1024 * 256;        // 524,288
  f16* X16h = (f16*)d_ws;
  f16* X16l = X16h + NE;
  f16* WTh  = X16l + NE;
  f16* WTl  = WTh + WE;
  f16* Qh   = WTl + WE;
  f16* Ql   = Qh + NE;
  f16* Kh   = Ql + NE / 2;
  f16* Kl   = Kh + NE;
  f16* Vt   = Kl + NE / 2;
  f16* A16  = Vt + NE;

  prep_split<<<dim3(1280), 256, 0, stream>>>(
      img, rad, Wq_img, Wkv_img, Wp_img, Wq_rad, Wkv_rad, Wp_rad,
      X16h, X16l, WTh, WTl);

  dim3 gp(6, 36, 2 * NB);
  proj_qkv_mfma<<<gp, 256, 0, stream>>>(X16h, X16l, WTh, WTl,
                                        Qh, Ql, Kh, Kl, Vt);

  dim3 ga(NSEQ / 128, NB * NHEAD, 2);
  attn_mfma<<<ga, 256, 0, stream>>>(Qh, Ql, Kh, Kl, Vt, U, A16);

  dim3 go(2, 36, 2 * NB);
  proj_out_mfma<<<go, 256, 0, stream>>>(A16, WTh, WTl, bp_img, bp_rad, out);
}